// Round 18
// baseline (101.524 us; speedup 1.0000x reference)
//
#include <hip/hip_runtime.h>
#include <hip/hip_bf16.h>

constexpr int BB = 32;    // batch
constexpr int TT = 512;   // decode steps
constexpr int NN = 512;   // nodes
constexpr int DD = 256;   // model dim
constexpr int HH = 8;     // heads
constexpr int DH = 32;    // head dim
#define NEG_INF (-1e9f)

// scale folds (applied at producer epilogues):
#define QSCL 0.25505872f   // 1/sqrt(32) * log2(e)
#define LSCL 0.18033688f   // 0.0625 * 2 * log2(e)
#define MBF16 ((ushort)0xCE6E)  // bf16(-1e9) sentinel (~-9.9967e8)

typedef __attribute__((ext_vector_type(8))) short bf16x8;
typedef __attribute__((ext_vector_type(4))) float f32x4;

__device__ inline float ex2(float x) { return __builtin_amdgcn_exp2f(x); }

__device__ inline ushort f2bf(float x) {
    union { float f; unsigned u; } c; c.f = x;
    unsigned u = c.u + 0x7fffu + ((c.u >> 16) & 1u);  // RNE
    return (ushort)(u >> 16);
}
__device__ inline uint pk2t(float a, float b) {  // truncating pack
    return __builtin_amdgcn_perm(__float_as_uint(b), __float_as_uint(a),
                                 0x07060302u);
}
__device__ inline ushort tr16(float x) { return (ushort)(__float_as_uint(x) >> 16); }
__device__ inline float bf2f(ushort u) {
    union { uint u; float f; } c; c.u = (uint)u << 16; return c.f;
}
// async global->LDS, 16B/lane; dest = wave-uniform base + lane*16 (m97/m173)
__device__ inline void gload_lds16(const void* g, void* l) {
    __builtin_amdgcn_global_load_lds(
        (const __attribute__((address_space(1))) unsigned int*)g,
        (__attribute__((address_space(3))) unsigned int*)l, 16, 0, 0);
}

// ---------------------------------------------------------------------------
// prep_all: [0,256) emb cvt+partials | [256,576) weight transposes |
//           [576,1600) mask bit-pack
__global__ __launch_bounds__(256) void prep_all_k(
    const float* __restrict__ emb, ushort* __restrict__ embB,
    float* __restrict__ partial, const float* __restrict__ Wn,
    const float* __restrict__ Ws, const float* __restrict__ Wo,
    ushort* __restrict__ WnT, ushort* __restrict__ WsT,
    ushort* __restrict__ WoT, const int* __restrict__ mask,
    uint* __restrict__ mbt) {
    int j = blockIdx.x;
    int tid = threadIdx.x;
    if (j < 256) {
        int b = j >> 3, part = j & 7, d = tid;
        const float* eb = emb + ((size_t)b * NN + part * 64) * DD + d;
        ushort* ob = embB + ((size_t)b * NN + part * 64) * DD + d;
        float s = 0.f;
        #pragma unroll 4
        for (int i = 0; i < 64; i++) {
            float v = eb[(size_t)i * DD];
            s += v;
            ob[(size_t)i * DD] = f2bf(v);
        }
        partial[((size_t)b * 8 + part) * DD + d] = s;
    } else if (j < 576) {
        __shared__ float t[32][33];
        int g = j - 256;
        int gx = g % 40, gy = g / 40;
        const float* W;
        ushort* WT;
        int NC, xb;
        if (gx < 24)      { W = Wn; WT = WnT; NC = 768; xb = gx; }
        else if (gx < 32) { W = Ws; WT = WsT; NC = 256; xb = gx - 24; }
        else              { W = Wo; WT = WoT; NC = 256; xb = gx - 32; }
        int tx = tid & 31, ty = tid >> 5;
        int x = xb * 32 + tx;
        int y0 = gy * 32;
        #pragma unroll
        for (int i = 0; i < 4; i++)
            t[ty + i * 8][tx] = W[(size_t)(y0 + ty + i * 8) * NC + x];
        __syncthreads();
        #pragma unroll
        for (int i = 0; i < 4; i++)
            WT[(size_t)(xb * 32 + ty + i * 8) * 256 + y0 + tx] =
                f2bf(t[tx][ty + i * 8]);
    } else {
        int idx = (j - 576) * 256 + tid;
        int row = idx >> 4, w = idx & 15;
        const int* mr = mask + (size_t)row * NN + w;
        uint u = 0;
        #pragma unroll
        for (int c = 0; c < 32; c++) u |= (uint)(mr[c * 16] != 0) << c;
        mbt[idx] = u;
    }
}

// ---------------------------------------------------------------------------
// gemm3: BM=128 x BN=64 x BK=64, async-dbuf staging (verified r15-r17).
// XCD-chunked. TASK 0: j<1536 K1 (proj; lk pre-scaled by LSCL);
//                j>=1536 K2 (gq = (emb[cur]@Ws + ctx)*QSCL, in-block ctx).
// TASK 1: K4 (glimpse = heads @ Wo).
template <int TASK>
__global__ __launch_bounds__(256) void gemm3_k(
    const ushort* __restrict__ A0, const ushort* __restrict__ WT0,
    const ushort* __restrict__ WT1, ushort* __restrict__ O0,
    ushort* __restrict__ O1, ushort* __restrict__ O2,
    ushort* __restrict__ O3, const float* __restrict__ partial,
    const float* __restrict__ Wf, const int* __restrict__ cur) {
    int j = blockIdx.x;
    bool k2 = (TASK == 0) && (j >= 1536);
    int bx, by;
    if (TASK == 0 && !k2) {
        int x = j & 7, t = j >> 3;           // t in [0,192)
        bx = x * 16 + t / 12; by = t % 12;
    } else {
        int jj = k2 ? j - 1536 : j;
        int x = jj & 7, t = jj >> 3;         // t in [0,64)
        bx = x * 16 + (t >> 2); by = t & 3;
    }
    int row0 = bx * 128, col0 = by * 64;
    int tid = threadIdx.x;
    int w = tid >> 6, l = tid & 63;
    int lo = l & 15, hi = l >> 4;

    __shared__ ushort As[2][128 * 64];  // 2 x 16KB
    __shared__ ushort Bs[2][64 * 64];   // 2 x 8KB
    __shared__ float ctxs[64];

    const ushort* WT = k2 ? WT1 : WT0;

    auto stage = [&](int buf, int kk) {
        #pragma unroll
        for (int i = 0; i < 4; i++) {
            int u = i * 256 + tid;
            int row = u >> 3, slot = u & 7;
            int arow = row0 + row;
            const ushort* ap;
            if (k2) {
                int b = arow >> 9;
                ap = A0 + ((size_t)(b * NN + cur[arow])) * DD;
            } else {
                ap = A0 + (size_t)arow * DD;
            }
            const void* gsrc = ap + kk * 64 + ((slot ^ (row & 7)) << 3);
            void* ldst = (char*)&As[buf][0] + i * 4096 + w * 1024;
            gload_lds16(gsrc, ldst);
        }
        #pragma unroll
        for (int i = 0; i < 2; i++) {
            int u = i * 256 + tid;
            int row = u >> 3, slot = u & 7;
            const void* gsrc =
                WT + (size_t)(col0 + row) * 256 + kk * 64 + ((slot ^ (row & 7)) << 3);
            void* ldst = (char*)&Bs[buf][0] + i * 4096 + w * 1024;
            gload_lds16(gsrc, ldst);
        }
    };

    const f32x4 zero = {0.f, 0.f, 0.f, 0.f};
    f32x4 acc[2][4] = {{zero, zero, zero, zero}, {zero, zero, zero, zero}};

    stage(0, 0);
    __syncthreads();
    #pragma unroll
    for (int kk = 0; kk < 4; kk++) {
        if (kk < 3) stage((kk + 1) & 1, kk + 1);
        int cb = kk & 1;
        #pragma unroll
        for (int ks = 0; ks < 2; ks++) {
            int sx = ((ks * 4 + hi) ^ (lo & 7)) << 4;
            bf16x8 af0 = *(const bf16x8*)((char*)&As[cb][0] + (w * 32 + lo) * 128 + sx);
            bf16x8 af1 = *(const bf16x8*)((char*)&As[cb][0] + (w * 32 + 16 + lo) * 128 + sx);
            #pragma unroll
            for (int c = 0; c < 4; c++) {
                bf16x8 bf = *(const bf16x8*)((char*)&Bs[cb][0] + (c * 16 + lo) * 128 + sx);
                acc[0][c] = __builtin_amdgcn_mfma_f32_16x16x32_bf16(af0, bf, acc[0][c], 0, 0, 0);
                acc[1][c] = __builtin_amdgcn_mfma_f32_16x16x32_bf16(af1, bf, acc[1][c], 0, 0, 0);
            }
        }
        __syncthreads();
    }

    int bbq = row0 >> 9;
    if (k2) {
        // in-block ctx: ctx[col] = (sum_p partial[b][p][:]/512) @ Wf[:, col]
        float* fs = (float*)&As[0][0];
        float mk = 0.f;
        #pragma unroll
        for (int p = 0; p < 8; p++)
            mk += partial[(size_t)bbq * 2048 + p * 256 + tid];
        fs[tid] = mk * (1.0f / 512.0f);
        __syncthreads();
        int cc = tid & 63, part = tid >> 6;
        float cs = 0.f;
        #pragma unroll 16
        for (int k = part * 64; k < part * 64 + 64; k++)
            cs += fs[k] * Wf[(size_t)k * 256 + col0 + cc];
        float* fs2 = fs + 256;
        fs2[part * 64 + cc] = cs;
        __syncthreads();
        if (tid < 64)
            ctxs[tid] = fs2[tid] + fs2[64 + tid] + fs2[128 + tid] + fs2[192 + tid];
        __syncthreads();
    }

    #pragma unroll
    for (int rg = 0; rg < 2; rg++) {
        int rw0 = row0 + w * 32 + rg * 16;
        int bb = rw0 >> 9;
        #pragma unroll
        for (int c = 0; c < 4; c++) {
            int col = col0 + c * 16 + lo;
            float v[4];
            #pragma unroll
            for (int r = 0; r < 4; r++) v[r] = acc[rg][c][r];
            if constexpr (TASK == 0) {
                if (k2) {
                    float bv = ctxs[col - col0];
                    #pragma unroll
                    for (int r = 0; r < 4; r++)
                        O3[(size_t)(rw0 + 4 * hi + r) * DD + col] =
                            f2bf((v[r] + bv) * QSCL);
                } else if (col < 256) {
                    int head = col >> 5, dh = col & 31;
                    #pragma unroll
                    for (int r = 0; r < 4; r++) {
                        int n = (rw0 + 4 * hi + r) & (NN - 1);
                        O0[(((size_t)(bb * HH + head) * NN + n) << 5) + dh] = f2bf(v[r]);
                    }
                } else if (col < 512) {
                    int cc2 = col - 256;
                    int bhv = bb * HH + (cc2 >> 5);
                    int dh = cc2 & 31;
                    int n0 = (rw0 + 4 * hi) & (NN - 1);
                    int m = n0 >> 2;
                    int p_ = m >> 3, s_ = (m >> 2) & 1, g_ = m & 3;
                    int n0p = (8 * p_ + 2 * g_ + s_) << 2;
                    ushort4 uv = {f2bf(v[0]), f2bf(v[1]), f2bf(v[2]), f2bf(v[3])};
                    *(ushort4*)(O1 + ((size_t)bhv * DH + dh) * NN + n0p) = uv;
                } else {
                    #pragma unroll
                    for (int r = 0; r < 4; r++)
                        O2[(size_t)(rw0 + 4 * hi + r) * 256 + (col - 512)] =
                            f2bf(v[r] * LSCL);
                }
            } else {
                #pragma unroll
                for (int r = 0; r < 4; r++)
                    O0[(size_t)(rw0 + 4 * hi + r) * DD + col] = f2bf(v[r]);
            }
        }
    }
}

// ---------------------------------------------------------------------------
// K3: two-phase LDS-staged swapped-operand attention, 128 q-rows/block,
// 4 blocks/CU (verified r14-r17). This round: K/V staging via async
// global_load_lds with inverse-swizzled per-lane SOURCE (linear LDS dest;
// rule #21 both-sides pairing with the r8-verified read swizzles).
__global__ __launch_bounds__(256, 4) void attn12_k(
    const ushort* __restrict__ gq, const ushort* __restrict__ gkT,
    const ushort* __restrict__ vTp, const uint* __restrict__ mbt,
    ushort* __restrict__ headsB) {
    int j = blockIdx.x;
    int bh = j & 255, quarter = j >> 8;
    int b = bh >> 3, h = bh & 7;
    int tid = threadIdx.x;
    int w = tid >> 6, l = tid & 63;
    int lo = l & 15, hi = l >> 4;

    __shared__ ushort Ks[8192];       // 16KB: read addr = lin ^ ((lin>>2)&0x70)
    __shared__ ushort Vs[8192];       // 16KB: read addr = lin ^ ((lin>>5)&0x70)
    __shared__ ushort OT[4][16][40];  // 5KB transpose staging

    const f32x4 zero = {0.f, 0.f, 0.f, 0.f};
    const bf16x8 ones = {(short)0x3F80, (short)0x3F80, (short)0x3F80,
                         (short)0x3F80, (short)0x3F80, (short)0x3F80,
                         (short)0x3F80, (short)0x3F80};
    int q0 = quarter * 128;
    int kswz = (lo & 7) << 4;

    // hoisted Q fragments + mask words (same both phases)
    bf16x8 qf0 = *(const bf16x8*)(gq + ((size_t)(b * TT + q0 + w * 16 + lo)) * DD + h * DH + hi * 8);
    bf16x8 qf1 = *(const bf16x8*)(gq + ((size_t)(b * TT + q0 + 64 + w * 16 + lo)) * DD + h * DH + hi * 8);
    uint4 mq0 = *(const uint4*)(mbt + ((size_t)(b * TT + q0 + w * 16 + lo)) * 16 + 4 * hi);
    uint4 mq1 = *(const uint4*)(mbt + ((size_t)(b * TT + q0 + 64 + w * 16 + lo)) * 16 + 4 * hi);

    f32x4 o0[2] = {zero, zero};
    f32x4 o1[2] = {zero, zero};
    f32x4 osum[2] = {zero, zero};

    const char* kbase = (const char*)(gkT + (size_t)bh * (NN * DH));
    const char* vbase = (const char*)(vTp + (size_t)bh * (DH * NN));

    for (int ph = 0; ph < 2; ph++) {
        if (ph) __syncthreads();
        // K: LDS[x] = Kglob[x ^ (((x>>2)&0x70) ^ ((x>>4)&0x10))]
        {
            const char* ksrc = kbase + ph * 16384;
            #pragma unroll
            for (int i = 0; i < 4; i++) {
                int x = (i * 256 + tid) * 16;
                int g = x ^ (((x >> 2) & 0x70) ^ ((x >> 4) & 0x10));
                gload_lds16(ksrc + g, (char*)Ks + i * 4096 + w * 1024);
            }
        }
        // V: LDS[x] = Vglob[dh-row(x) + ((x&511) ^ ((x>>5)&0x70))]
        {
            const char* vsrc = vbase + ph * 512;
            #pragma unroll
            for (int i = 0; i < 4; i++) {
                int x = (i * 256 + tid) * 16;
                int g = ((x >> 9) << 10) + ((x & 511) ^ ((x >> 5) & 0x70));
                gload_lds16(vsrc + g, (char*)Vs + i * 4096 + w * 1024);
            }
        }
        __syncthreads();

        #pragma unroll
        for (int qc2 = 0; qc2 < 2; qc2++) {
            bf16x8 qf = qc2 ? qf1 : qf0;
            uint4 mq = qc2 ? mq1 : mq0;

            #pragma unroll 4
            for (int p = 0; p < 8; p++) {
                int nn = 32 * p + lo;
                bf16x8 kf0 = *(const bf16x8*)((char*)Ks + ((nn * 64 + hi * 16) ^ kswz));
                bf16x8 kf1 = *(const bf16x8*)((char*)Ks + (((nn + 16) * 64 + hi * 16) ^ kswz));
                __builtin_amdgcn_s_setprio(1);
                f32x4 s0 = __builtin_amdgcn_mfma_f32_16x16x32_bf16(kf0, qf, zero, 0, 0, 0);
                f32x4 s1 = __builtin_amdgcn_mfma_f32_16x16x32_bf16(kf1, qf, zero, 0, 0, 0);
                __builtin_amdgcn_s_setprio(0);
                union { bf16x8 v; uint u[4]; } pf;
                {
                    int c = ph * 16 + 2 * p;
                    float e0 = ((mq.x >> c) & 1u) ? ex2(s0[0]) : 0.f;
                    float e1 = ((mq.y >> c) & 1u) ? ex2(s0[1]) : 0.f;
                    float e2 = ((mq.z >> c) & 1u) ? ex2(s0[2]) : 0.f;
                    float e3 = ((mq.w >> c) & 1u) ? ex2(s0[3]) : 0.f;
                    pf.u[0] = pk2t(e0, e1);
                    pf.u[1] = pk2t(e2, e3);
                }
                {
                    int c = ph * 16 + 2 * p + 1;
                    float e0 = ((mq.x >> c) & 1u) ? ex2(s1[0]) : 0.f;
                    float e1 = ((mq.y >> c) & 1u) ? ex2(s1[1]) : 0.f;
                    float e2 = ((mq.z >> c) & 1u) ? ex2(s1[2]) : 0.f;
                    float e3 = ((mq.w >> c) & 1u) ? ex2(s1[3]) : 0.f;
                    pf.u[2] = pk2t(e0, e1);
                    pf.u[3] = pk2t(e2, e3);
                }
                int vo = (32 * p + 8 * hi) * 2;
                bf16x8 va0 = *(const bf16x8*)((char*)Vs + ((lo * 512 + vo) ^ kswz));
                bf16x8 va1 = *(const bf16x8*)((char*)Vs + (((lo + 16) * 512 + vo) ^ kswz));
                __builtin_amdgcn_s_setprio(1);
                o0[qc2] = __builtin_amdgcn_mfma_f32_16x16x32_bf16(va0, pf.v, o0[qc2], 0, 0, 0);
                o1[qc2] = __builtin_amdgcn_mfma_f32_16x16x32_bf16(va1, pf.v, o1[qc2], 0, 0, 0);
                osum[qc2] = __builtin_amdgcn_mfma_f32_16x16x32_bf16(ones, pf.v, osum[qc2], 0, 0, 0);
                __builtin_amdgcn_s_setprio(0);
            }
        }
    }

    #pragma unroll
    for (int qc2 = 0; qc2 < 2; qc2++) {
        int t0 = q0 + qc2 * 64 + w * 16;
        float inv = 1.0f / fmaxf(osum[qc2][0], 1e-30f);
        #pragma unroll
        for (int r = 0; r < 4; r++) {
            OT[w][lo][4 * hi + r] = tr16(o0[qc2][r] * inv);
            OT[w][lo][16 + 4 * hi + r] = tr16(o1[qc2][r] * inv);
        }
        bf16x8 ov = *(const bf16x8*)(&OT[w][lo][hi * 8]);
        *(bf16x8*)(headsB + ((size_t)(b * TT + t0 + lo)) * DD + h * DH + hi * 8) = ov;
    }
}

// ---------------------------------------------------------------------------
// K5a: pointer-logits GEMM (async dbuf). Writes logitsB PRE-MASKED (bf16
// -1e9 sentinel at masked cols) so fin needs no mask. XCD-chunked.
__global__ __launch_bounds__(256) void logits_mm_k(
    const ushort* __restrict__ glimpse, const ushort* __restrict__ lkb,
    const uint* __restrict__ mbt, ushort* __restrict__ logitsB,
    float* __restrict__ psum) {
    int j = blockIdx.x;  // 1024
    int x = j & 7, t = j >> 3;
    int b = x * 4 + (t >> 5);
    int rem = t & 31;
    int bx = rem >> 3, by = rem & 7;
    int row0 = bx * 128, col0 = by * 64;
    int tid = threadIdx.x;
    int w = tid >> 6, l = tid & 63;
    int lo = l & 15, hi = l >> 4;

    __shared__ ushort As[2][128 * 64];
    __shared__ ushort Bs[2][64 * 64];

    const ushort* Abase = glimpse + (size_t)b * TT * DD;
    const ushort* Bbase = lkb + (size_t)b * NN * DD;

    auto stage = [&](int buf, int kk) {
        #pragma unroll
        for (int i = 0; i < 4; i++) {
            int u = i * 256 + tid;
            int row = u >> 3, slot = u & 7;
            const void* gsrc =
                Abase + (size_t)(row0 + row) * DD + kk * 64 + ((slot ^ (row & 7)) << 3);
            void* ldst = (char*)&As[buf][0] + i * 4096 + w * 1024;
            gload_lds16(gsrc, ldst);
        }
        #pragma unroll
        for (int i = 0; i < 2; i++) {
            int u = i * 256 + tid;
            int row = u >> 3, slot = u & 7;
            const void* gsrc =
                Bbase + (size_t)(col0 + row) * DD + kk * 64 + ((slot ^ (row & 7)) << 3);
            void* ldst = (char*)&Bs[buf][0] + i * 4096 + w * 1024;
            gload_lds16(gsrc, ldst);
        }
    };

    const f32x4 zero = {0.f, 0.f, 0.f, 0.f};
    f32x4 acc[2][4] = {{zero, zero, zero, zero}, {zero, zero, zero, zero}};

    stage(0, 0);
    __syncthreads();
    #pragma unroll
    for (int kk = 0; kk < 4; kk++) {
        if (kk < 3) stage((kk + 1) & 1, kk + 1);
        int cb = kk & 1;
        #pragma unroll
        for (int ks = 0; ks < 2; ks++) {
            int sx = ((ks * 4 + hi) ^ (lo & 7)) << 4;
            bf16x8 af0 = *(const bf16x8*)((char*)&As[cb][0] + (w * 32 + lo) * 128 + sx);
            bf16x8 af1 = *(const bf16x8*)((char*)&As[cb][0] + (w * 32 + 16 + lo) * 128 + sx);
            #pragma unroll
            for (int c = 0; c < 4; c++) {
                bf16x8 bf = *(const bf16x8*)((char*)&Bs[cb][0] + (c * 16 + lo) * 128 + sx);
                acc[0][c] = __builtin_amdgcn_mfma_f32_16x16x32_bf16(af0, bf, acc[0][c], 0, 0, 0);
                acc[1][c] = __builtin_amdgcn_mfma_f32_16x16x32_bf16(af1, bf, acc[1][c], 0, 0, 0);
            }
        }
        __syncthreads();
    }

    #pragma unroll
    for (int rg = 0; rg < 2; rg++) {
        int rw = row0 + w * 32 + rg * 16;
        uint mw[4];
        #pragma unroll
        for (int r = 0; r < 4; r++)
            mw[r] = mbt[((size_t)(b * TT + rw + 4 * hi + r)) * 16 + lo];
        float rsum[4] = {0.f, 0.f, 0.f, 0.f};
        #pragma unroll
        for (int c = 0; c < 4; c++) {
            int col = col0 + c * 16 + lo;
            int cg = by * 4 + c;
            #pragma unroll
            for (int r = 0; r < 4; r++) {
                float y = fminf(fmaxf(acc[rg][c][r], -57.f), 57.f);
                float t2 = 10.f - 20.f / (ex2(y) + 1.f);
                uint bit = (mw[r] >> cg) & 1u;
                logitsB[((size_t)(b * TT + rw + 4 * hi + r)) * NN + col] =
                    bit ? tr16(t2) : MBF16;
                rsum[r] += bit ? __expf(t2 - 10.f) : 0.f;
            }
        }
        #pragma unroll
        for (int r = 0; r < 4; r++) {
            #pragma unroll
            for (int o = 1; o < 16; o <<= 1) rsum[r] += __shfl_xor(rsum[r], o);
        }
        if (lo == 0) {
            #pragma unroll
            for (int r = 0; r < 4; r++)
                psum[((size_t)(b * TT + rw + 4 * hi + r)) * 8 + by] = rsum[r];
        }
    }
}

// K5b: out = logit - lse (logitsB pre-masked), lse = 10 + log(sum8 psum).
__global__ __launch_bounds__(256) void logits_fin_k(
    const ushort* __restrict__ logitsB, const float* __restrict__ psum,
    float* __restrict__ out) {
    int r0 = blockIdx.x * 8;
    int tid = threadIdx.x;
    __shared__ float lsev[8];
    if (tid < 8) {
        const float* pp = psum + (size_t)(r0 + tid) * 8;
        float s = 0.f;
        #pragma unroll
        for (int p = 0; p < 8; p++) s += pp[p];
        lsev[tid] = 10.f + __logf(fmaxf(s, 1e-37f));
    }
    __syncthreads();
    int row = tid >> 5, n0 = (tid & 31) * 16;
    float lse = lsev[row];
    const ushort* lb = logitsB + (size_t)(r0 + row) * NN + n0;
    bf16x8 v0 = *(const bf16x8*)(lb);
    bf16x8 v1 = *(const bf16x8*)(lb + 8);
    float ov[16];
    #pragma unroll
    for (int jj = 0; jj < 16; jj++) {
        float lv = bf2f((ushort)(jj < 8 ? v0[jj] : v1[jj - 8]));
        ov[jj] = lv - lse;
    }
    float* ob = out + (size_t)(r0 + row) * NN + n0;
    #pragma unroll
    for (int q = 0; q < 4; q++)
        *(float4*)(ob + q * 4) = *(float4*)(&ov[q * 4]);
}

// ---------------------------------------------------------------------------
extern "C" void kernel_launch(void* const* d_in, const int* in_sizes, int n_in,
                              void* d_out, int out_size, void* d_ws,
                              size_t ws_size, hipStream_t stream) {
    const float* emb = (const float*)d_in[0];
    const int* cur   = (const int*)d_in[1];
    const int* mask  = (const int*)d_in[2];
    const float* Wn  = (const float*)d_in[3];
    const float* Wf  = (const float*)d_in[4];
    const float* Ws  = (const float*)d_in[5];
    const float* Wo  = (const float*)d_in[6];
    float* out = (float*)d_out;

    const size_t SLABE = (size_t)BB * NN * DD;
    ushort* embB     = (ushort*)d_ws;
    ushort* gkT      = embB + SLABE;     // [bh][n][32]
    ushort* vTp      = gkT + SLABE;      // [bh][dh][n''] pre-permuted
    ushort* lkb      = vTp + SLABE;      // [b*N+n][256], pre-scaled by LSCL
    ushort* gq       = lkb + SLABE;      // [b*T+t][256], pre-scaled by QSCL
    ushort* headsB   = gq + SLABE;
    ushort* glimpseB = headsB + SLABE;
    ushort* WnT      = glimpseB + SLABE;
    ushort* WsT      = WnT + 768 * 256;
    ushort* WoT      = WsT + 256 * 256;
    uint*   mbt      = (uint*)(WoT + 256 * 256);
    float*  partial  = (float*)(mbt + (size_t)BB * TT * 16);
    // K5 scratch reuses embB/gkT/vTp region (dead after attn12):
    ushort* logitsB  = embB;                       // 16.8 MB
    float*  psum     = (float*)(embB + (size_t)BB * TT * NN);  // 512 KB

    prep_all_k<<<1600, 256, 0, stream>>>(emb, embB, partial, Wn, Ws, Wo,
                                         WnT, WsT, WoT, mask, mbt);
    gemm3_k<0><<<2048, 256, 0, stream>>>(embB, WnT, WsT, gkT, vTp, lkb, gq,
                                         partial, Wf, cur);
    attn12_k<<<1024, 256, 0, stream>>>(gq, gkT, vTp, mbt, headsB);
    gemm3_k<1><<<512, 256, 0, stream>>>(headsB, WoT, nullptr, glimpseB,
                                        nullptr, nullptr, nullptr, nullptr,
                                        nullptr, nullptr);
    logits_mm_k<<<1024, 256, 0, stream>>>(glimpseB, lkb, mbt, logitsB, psum);
    logits_fin_k<<<BB * TT / 8, 256, 0, stream>>>(logitsB, psum, out);
}

// Round 19
// 95.709 us; speedup vs baseline: 1.0608x; 1.0608x over previous
//
#include <hip/hip_runtime.h>
#include <hip/hip_bf16.h>

constexpr int BB = 32;    // batch
constexpr int TT = 512;   // decode steps
constexpr int NN = 512;   // nodes
constexpr int DD = 256;   // model dim
constexpr int HH = 8;     // heads
constexpr int DH = 32;    // head dim
#define NEG_INF (-1e9f)

// scale folds (applied at producer epilogues):
#define QSCL 0.25505872f   // 1/sqrt(32) * log2(e)
#define LSCL 0.18033688f   // 0.0625 * 2 * log2(e)

typedef __attribute__((ext_vector_type(8))) short bf16x8;
typedef __attribute__((ext_vector_type(4))) float f32x4;

__device__ inline float ex2(float x) { return __builtin_amdgcn_exp2f(x); }

__device__ inline ushort f2bf(float x) {
    union { float f; unsigned u; } c; c.f = x;
    unsigned u = c.u + 0x7fffu + ((c.u >> 16) & 1u);  // RNE
    return (ushort)(u >> 16);
}
__device__ inline uint pk2t(float a, float b) {  // truncating pack
    return __builtin_amdgcn_perm(__float_as_uint(b), __float_as_uint(a),
                                 0x07060302u);
}
__device__ inline ushort tr16(float x) { return (ushort)(__float_as_uint(x) >> 16); }
__device__ inline float ulo(uint u) {
    union { uint u; float f; } c; c.u = u << 16; return c.f;
}
__device__ inline float uhi(uint u) {
    union { uint u; float f; } c; c.u = u & 0xffff0000u; return c.f;
}
// async global->LDS, 16B/lane; dest = wave-uniform base + lane*16 (m97/m173)
__device__ inline void gload_lds16(const void* g, void* l) {
    __builtin_amdgcn_global_load_lds(
        (const __attribute__((address_space(1))) unsigned int*)g,
        (__attribute__((address_space(3))) unsigned int*)l, 16, 0, 0);
}

// ---------------------------------------------------------------------------
// prep_all: [0,256) emb cvt+partials | [256,576) weight transposes |
//           [576,1600) mask bit-pack
__global__ __launch_bounds__(256) void prep_all_k(
    const float* __restrict__ emb, ushort* __restrict__ embB,
    float* __restrict__ partial, const float* __restrict__ Wn,
    const float* __restrict__ Ws, const float* __restrict__ Wo,
    ushort* __restrict__ WnT, ushort* __restrict__ WsT,
    ushort* __restrict__ WoT, const int* __restrict__ mask,
    uint* __restrict__ mbt) {
    int j = blockIdx.x;
    int tid = threadIdx.x;
    if (j < 256) {
        int b = j >> 3, part = j & 7, d = tid;
        const float* eb = emb + ((size_t)b * NN + part * 64) * DD + d;
        ushort* ob = embB + ((size_t)b * NN + part * 64) * DD + d;
        float s = 0.f;
        #pragma unroll 4
        for (int i = 0; i < 64; i++) {
            float v = eb[(size_t)i * DD];
            s += v;
            ob[(size_t)i * DD] = f2bf(v);
        }
        partial[((size_t)b * 8 + part) * DD + d] = s;
    } else if (j < 576) {
        __shared__ float t[32][33];
        int g = j - 256;
        int gx = g % 40, gy = g / 40;
        const float* W;
        ushort* WT;
        int NC, xb;
        if (gx < 24)      { W = Wn; WT = WnT; NC = 768; xb = gx; }
        else if (gx < 32) { W = Ws; WT = WsT; NC = 256; xb = gx - 24; }
        else              { W = Wo; WT = WoT; NC = 256; xb = gx - 32; }
        int tx = tid & 31, ty = tid >> 5;
        int x = xb * 32 + tx;
        int y0 = gy * 32;
        #pragma unroll
        for (int i = 0; i < 4; i++)
            t[ty + i * 8][tx] = W[(size_t)(y0 + ty + i * 8) * NC + x];
        __syncthreads();
        #pragma unroll
        for (int i = 0; i < 4; i++)
            WT[(size_t)(xb * 32 + ty + i * 8) * 256 + y0 + tx] =
                f2bf(t[tx][ty + i * 8]);
    } else {
        int idx = (j - 576) * 256 + tid;
        int row = idx >> 4, w = idx & 15;
        const int* mr = mask + (size_t)row * NN + w;
        uint u = 0;
        #pragma unroll
        for (int c = 0; c < 32; c++) u |= (uint)(mr[c * 16] != 0) << c;
        mbt[idx] = u;
    }
}

// ---------------------------------------------------------------------------
// gemm3: BM=128 x BN=64 x BK=64, async-dbuf staging (verified r15-r18).
// XCD-chunked. TASK 0: j<1536 K1 (proj; lk pre-scaled by LSCL);
//                j>=1536 K2 (gq = (emb[cur]@Ws + ctx)*QSCL, in-block ctx).
// TASK 1: K4 (glimpse = heads @ Wo).
template <int TASK>
__global__ __launch_bounds__(256) void gemm3_k(
    const ushort* __restrict__ A0, const ushort* __restrict__ WT0,
    const ushort* __restrict__ WT1, ushort* __restrict__ O0,
    ushort* __restrict__ O1, ushort* __restrict__ O2,
    ushort* __restrict__ O3, const float* __restrict__ partial,
    const float* __restrict__ Wf, const int* __restrict__ cur) {
    int j = blockIdx.x;
    bool k2 = (TASK == 0) && (j >= 1536);
    int bx, by;
    if (TASK == 0 && !k2) {
        int x = j & 7, t = j >> 3;           // t in [0,192)
        bx = x * 16 + t / 12; by = t % 12;
    } else {
        int jj = k2 ? j - 1536 : j;
        int x = jj & 7, t = jj >> 3;         // t in [0,64)
        bx = x * 16 + (t >> 2); by = t & 3;
    }
    int row0 = bx * 128, col0 = by * 64;
    int tid = threadIdx.x;
    int w = tid >> 6, l = tid & 63;
    int lo = l & 15, hi = l >> 4;

    __shared__ ushort As[2][128 * 64];  // 2 x 16KB
    __shared__ ushort Bs[2][64 * 64];   // 2 x 8KB
    __shared__ float ctxs[64];

    const ushort* WT = k2 ? WT1 : WT0;

    auto stage = [&](int buf, int kk) {
        #pragma unroll
        for (int i = 0; i < 4; i++) {
            int u = i * 256 + tid;
            int row = u >> 3, slot = u & 7;
            int arow = row0 + row;
            const ushort* ap;
            if (k2) {
                int b = arow >> 9;
                ap = A0 + ((size_t)(b * NN + cur[arow])) * DD;
            } else {
                ap = A0 + (size_t)arow * DD;
            }
            const void* gsrc = ap + kk * 64 + ((slot ^ (row & 7)) << 3);
            void* ldst = (char*)&As[buf][0] + i * 4096 + w * 1024;
            gload_lds16(gsrc, ldst);
        }
        #pragma unroll
        for (int i = 0; i < 2; i++) {
            int u = i * 256 + tid;
            int row = u >> 3, slot = u & 7;
            const void* gsrc =
                WT + (size_t)(col0 + row) * 256 + kk * 64 + ((slot ^ (row & 7)) << 3);
            void* ldst = (char*)&Bs[buf][0] + i * 4096 + w * 1024;
            gload_lds16(gsrc, ldst);
        }
    };

    const f32x4 zero = {0.f, 0.f, 0.f, 0.f};
    f32x4 acc[2][4] = {{zero, zero, zero, zero}, {zero, zero, zero, zero}};

    stage(0, 0);
    __syncthreads();
    #pragma unroll
    for (int kk = 0; kk < 4; kk++) {
        if (kk < 3) stage((kk + 1) & 1, kk + 1);
        int cb = kk & 1;
        #pragma unroll
        for (int ks = 0; ks < 2; ks++) {
            int sx = ((ks * 4 + hi) ^ (lo & 7)) << 4;
            bf16x8 af0 = *(const bf16x8*)((char*)&As[cb][0] + (w * 32 + lo) * 128 + sx);
            bf16x8 af1 = *(const bf16x8*)((char*)&As[cb][0] + (w * 32 + 16 + lo) * 128 + sx);
            #pragma unroll
            for (int c = 0; c < 4; c++) {
                bf16x8 bf = *(const bf16x8*)((char*)&Bs[cb][0] + (c * 16 + lo) * 128 + sx);
                acc[0][c] = __builtin_amdgcn_mfma_f32_16x16x32_bf16(af0, bf, acc[0][c], 0, 0, 0);
                acc[1][c] = __builtin_amdgcn_mfma_f32_16x16x32_bf16(af1, bf, acc[1][c], 0, 0, 0);
            }
        }
        __syncthreads();
    }

    int bbq = row0 >> 9;
    if (k2) {
        // in-block ctx: ctx[col] = (sum_p partial[b][p][:]/512) @ Wf[:, col]
        float* fs = (float*)&As[0][0];
        float mk = 0.f;
        #pragma unroll
        for (int p = 0; p < 8; p++)
            mk += partial[(size_t)bbq * 2048 + p * 256 + tid];
        fs[tid] = mk * (1.0f / 512.0f);
        __syncthreads();
        int cc = tid & 63, part = tid >> 6;
        float cs = 0.f;
        #pragma unroll 16
        for (int k = part * 64; k < part * 64 + 64; k++)
            cs += fs[k] * Wf[(size_t)k * 256 + col0 + cc];
        float* fs2 = fs + 256;
        fs2[part * 64 + cc] = cs;
        __syncthreads();
        if (tid < 64)
            ctxs[tid] = fs2[tid] + fs2[64 + tid] + fs2[128 + tid] + fs2[192 + tid];
        __syncthreads();
    }

    #pragma unroll
    for (int rg = 0; rg < 2; rg++) {
        int rw0 = row0 + w * 32 + rg * 16;
        int bb = rw0 >> 9;
        #pragma unroll
        for (int c = 0; c < 4; c++) {
            int col = col0 + c * 16 + lo;
            float v[4];
            #pragma unroll
            for (int r = 0; r < 4; r++) v[r] = acc[rg][c][r];
            if constexpr (TASK == 0) {
                if (k2) {
                    float bv = ctxs[col - col0];
                    #pragma unroll
                    for (int r = 0; r < 4; r++)
                        O3[(size_t)(rw0 + 4 * hi + r) * DD + col] =
                            f2bf((v[r] + bv) * QSCL);
                } else if (col < 256) {
                    int head = col >> 5, dh = col & 31;
                    #pragma unroll
                    for (int r = 0; r < 4; r++) {
                        int n = (rw0 + 4 * hi + r) & (NN - 1);
                        O0[(((size_t)(bb * HH + head) * NN + n) << 5) + dh] = f2bf(v[r]);
                    }
                } else if (col < 512) {
                    int cc2 = col - 256;
                    int bhv = bb * HH + (cc2 >> 5);
                    int dh = cc2 & 31;
                    int n0 = (rw0 + 4 * hi) & (NN - 1);
                    int m = n0 >> 2;
                    int p_ = m >> 3, s_ = (m >> 2) & 1, g_ = m & 3;
                    int n0p = (8 * p_ + 2 * g_ + s_) << 2;
                    ushort4 uv = {f2bf(v[0]), f2bf(v[1]), f2bf(v[2]), f2bf(v[3])};
                    *(ushort4*)(O1 + ((size_t)bhv * DH + dh) * NN + n0p) = uv;
                } else {
                    #pragma unroll
                    for (int r = 0; r < 4; r++)
                        O2[(size_t)(rw0 + 4 * hi + r) * 256 + (col - 512)] =
                            f2bf(v[r] * LSCL);
                }
            } else {
                #pragma unroll
                for (int r = 0; r < 4; r++)
                    O0[(size_t)(rw0 + 4 * hi + r) * DD + col] = f2bf(v[r]);
            }
        }
    }
}

// ---------------------------------------------------------------------------
// K3: two-phase LDS-staged swapped-operand attention (verified r14-r18).
__global__ __launch_bounds__(256, 4) void attn12_k(
    const ushort* __restrict__ gq, const ushort* __restrict__ gkT,
    const ushort* __restrict__ vTp, const uint* __restrict__ mbt,
    ushort* __restrict__ headsB) {
    int j = blockIdx.x;
    int bh = j & 255, quarter = j >> 8;
    int b = bh >> 3, h = bh & 7;
    int tid = threadIdx.x;
    int w = tid >> 6, l = tid & 63;
    int lo = l & 15, hi = l >> 4;

    __shared__ ushort Ks[8192];       // 16KB: read addr = lin ^ ((lin>>2)&0x70)
    __shared__ ushort Vs[8192];       // 16KB: read addr = lin ^ ((lin>>5)&0x70)
    __shared__ ushort OT[4][16][40];  // 5KB transpose staging

    const f32x4 zero = {0.f, 0.f, 0.f, 0.f};
    const bf16x8 ones = {(short)0x3F80, (short)0x3F80, (short)0x3F80,
                         (short)0x3F80, (short)0x3F80, (short)0x3F80,
                         (short)0x3F80, (short)0x3F80};
    int q0 = quarter * 128;
    int kswz = (lo & 7) << 4;

    bf16x8 qf0 = *(const bf16x8*)(gq + ((size_t)(b * TT + q0 + w * 16 + lo)) * DD + h * DH + hi * 8);
    bf16x8 qf1 = *(const bf16x8*)(gq + ((size_t)(b * TT + q0 + 64 + w * 16 + lo)) * DD + h * DH + hi * 8);
    uint4 mq0 = *(const uint4*)(mbt + ((size_t)(b * TT + q0 + w * 16 + lo)) * 16 + 4 * hi);
    uint4 mq1 = *(const uint4*)(mbt + ((size_t)(b * TT + q0 + 64 + w * 16 + lo)) * 16 + 4 * hi);

    f32x4 o0[2] = {zero, zero};
    f32x4 o1[2] = {zero, zero};
    f32x4 osum[2] = {zero, zero};

    const char* kbase = (const char*)(gkT + (size_t)bh * (NN * DH));
    const char* vbase = (const char*)(vTp + (size_t)bh * (DH * NN));

    for (int ph = 0; ph < 2; ph++) {
        if (ph) __syncthreads();
        {
            const char* ksrc = kbase + ph * 16384;
            #pragma unroll
            for (int i = 0; i < 4; i++) {
                int x = (i * 256 + tid) * 16;
                int g = x ^ (((x >> 2) & 0x70) ^ ((x >> 4) & 0x10));
                gload_lds16(ksrc + g, (char*)Ks + i * 4096 + w * 1024);
            }
        }
        {
            const char* vsrc = vbase + ph * 512;
            #pragma unroll
            for (int i = 0; i < 4; i++) {
                int x = (i * 256 + tid) * 16;
                int g = ((x >> 9) << 10) + ((x & 511) ^ ((x >> 5) & 0x70));
                gload_lds16(vsrc + g, (char*)Vs + i * 4096 + w * 1024);
            }
        }
        __syncthreads();

        #pragma unroll
        for (int qc2 = 0; qc2 < 2; qc2++) {
            bf16x8 qf = qc2 ? qf1 : qf0;
            uint4 mq = qc2 ? mq1 : mq0;

            #pragma unroll 4
            for (int p = 0; p < 8; p++) {
                int nn = 32 * p + lo;
                bf16x8 kf0 = *(const bf16x8*)((char*)Ks + ((nn * 64 + hi * 16) ^ kswz));
                bf16x8 kf1 = *(const bf16x8*)((char*)Ks + (((nn + 16) * 64 + hi * 16) ^ kswz));
                __builtin_amdgcn_s_setprio(1);
                f32x4 s0 = __builtin_amdgcn_mfma_f32_16x16x32_bf16(kf0, qf, zero, 0, 0, 0);
                f32x4 s1 = __builtin_amdgcn_mfma_f32_16x16x32_bf16(kf1, qf, zero, 0, 0, 0);
                __builtin_amdgcn_s_setprio(0);
                union { bf16x8 v; uint u[4]; } pf;
                {
                    int c = ph * 16 + 2 * p;
                    float e0 = ((mq.x >> c) & 1u) ? ex2(s0[0]) : 0.f;
                    float e1 = ((mq.y >> c) & 1u) ? ex2(s0[1]) : 0.f;
                    float e2 = ((mq.z >> c) & 1u) ? ex2(s0[2]) : 0.f;
                    float e3 = ((mq.w >> c) & 1u) ? ex2(s0[3]) : 0.f;
                    pf.u[0] = pk2t(e0, e1);
                    pf.u[1] = pk2t(e2, e3);
                }
                {
                    int c = ph * 16 + 2 * p + 1;
                    float e0 = ((mq.x >> c) & 1u) ? ex2(s1[0]) : 0.f;
                    float e1 = ((mq.y >> c) & 1u) ? ex2(s1[1]) : 0.f;
                    float e2 = ((mq.z >> c) & 1u) ? ex2(s1[2]) : 0.f;
                    float e3 = ((mq.w >> c) & 1u) ? ex2(s1[3]) : 0.f;
                    pf.u[2] = pk2t(e0, e1);
                    pf.u[3] = pk2t(e2, e3);
                }
                int vo = (32 * p + 8 * hi) * 2;
                bf16x8 va0 = *(const bf16x8*)((char*)Vs + ((lo * 512 + vo) ^ kswz));
                bf16x8 va1 = *(const bf16x8*)((char*)Vs + (((lo + 16) * 512 + vo) ^ kswz));
                __builtin_amdgcn_s_setprio(1);
                o0[qc2] = __builtin_amdgcn_mfma_f32_16x16x32_bf16(va0, pf.v, o0[qc2], 0, 0, 0);
                o1[qc2] = __builtin_amdgcn_mfma_f32_16x16x32_bf16(va1, pf.v, o1[qc2], 0, 0, 0);
                osum[qc2] = __builtin_amdgcn_mfma_f32_16x16x32_bf16(ones, pf.v, osum[qc2], 0, 0, 0);
                __builtin_amdgcn_s_setprio(0);
            }
        }
    }

    #pragma unroll
    for (int qc2 = 0; qc2 < 2; qc2++) {
        int t0 = q0 + qc2 * 64 + w * 16;
        float inv = 1.0f / fmaxf(osum[qc2][0], 1e-30f);
        #pragma unroll
        for (int r = 0; r < 4; r++) {
            OT[w][lo][4 * hi + r] = tr16(o0[qc2][r] * inv);
            OT[w][lo][16 + 4 * hi + r] = tr16(o1[qc2][r] * inv);
        }
        bf16x8 ov = *(const bf16x8*)(&OT[w][lo][hi * 8]);
        *(bf16x8*)(headsB + ((size_t)(b * TT + t0 + lo)) * DD + h * DH + hi * 8) = ov;
    }
}

// ---------------------------------------------------------------------------
// K5 (single pass): full-row pointer logits + log_softmax, f32 out direct.
// Block = 32 rows x all 512 cols. A staged once (16KB); lk panels (64 rows)
// through a 2x32KB async double buffer. Wave w owns col-chunk w of each
// panel (c = p*4 + w). XCD-chunked: x=j&7 owns 4 batches (lk L2-resident).
__global__ __launch_bounds__(256) void logits7_k(
    const ushort* __restrict__ glimpse, const ushort* __restrict__ lkb,
    const uint* __restrict__ mbt, float* __restrict__ out) {
    int j = blockIdx.x;  // 512
    int x = j & 7, t = j >> 3;       // t in [0,64)
    int b = x * 4 + (t >> 4);
    int row0 = (t & 15) * 32;
    int tid = threadIdx.x;
    int w = tid >> 6, l = tid & 63;
    int lo = l & 15, hi = l >> 4;

    __shared__ ushort As[32 * 256];     // 16KB, 512B rows, swz ((row&7)<<4)
    __shared__ ushort Bs[2][64 * 256];  // 64KB, same row swizzle
    __shared__ float reds[4][2][16];

    const ushort* Abase = glimpse + ((size_t)b * TT + row0) * DD;
    const ushort* Bbase = lkb + (size_t)b * NN * DD;
    int kswz = (lo & 7) << 4;

    // stage A: 1024 x 16B units, linear LDS + inverse-swizzled source
    // (512B rows: involution g = x ^ ((x>>5)&0x70), verified r18 attn-V)
    #pragma unroll
    for (int i = 0; i < 4; i++) {
        int xx = (i * 256 + tid) * 16;
        int g = xx ^ ((xx >> 5) & 0x70);
        gload_lds16((const char*)Abase + g, (char*)As + i * 4096 + w * 1024);
    }
    auto stageB = [&](int buf, int p) {
        const char* src = (const char*)(Bbase + (size_t)p * 64 * DD);
        #pragma unroll
        for (int i = 0; i < 8; i++) {
            int xx = (i * 256 + tid) * 16;
            int g = xx ^ ((xx >> 5) & 0x70);
            gload_lds16(src + g, (char*)&Bs[buf][0] + i * 4096 + w * 1024);
        }
    };
    stageB(0, 0);
    __syncthreads();

    // hoisted A fragments (rows rg*16+lo), reused across all 8 panels
    bf16x8 af0[8], af1[8];
    #pragma unroll
    for (int ks = 0; ks < 8; ks++) {
        int sx = ((ks * 4 + hi) << 4) ^ kswz;
        af0[ks] = *(const bf16x8*)((char*)As + lo * 512 + sx);
        af1[ks] = *(const bf16x8*)((char*)As + (16 + lo) * 512 + sx);
    }
    uint mw0[4], mw1[4];
    #pragma unroll
    for (int r = 0; r < 4; r++) {
        mw0[r] = mbt[((size_t)(b * TT + row0 + 4 * hi + r)) * 16 + lo];
        mw1[r] = mbt[((size_t)(b * TT + row0 + 16 + 4 * hi + r)) * 16 + lo];
    }

    const f32x4 zero = {0.f, 0.f, 0.f, 0.f};
    float sum0[4] = {0.f, 0.f, 0.f, 0.f}, sum1[4] = {0.f, 0.f, 0.f, 0.f};
    uint tuA[8], tuB[8], tuC[8], tuD[8];

    #pragma unroll
    for (int p = 0; p < 8; p++) {
        if (p < 7) stageB((p + 1) & 1, p + 1);  // in flight over MFMAs
        int cb = p & 1;
        f32x4 a0 = zero, a1 = zero;
        #pragma unroll
        for (int ks = 0; ks < 8; ks++) {
            int sx = ((ks * 4 + hi) << 4) ^ kswz;
            bf16x8 bf = *(const bf16x8*)((char*)&Bs[cb][0] + (w * 16 + lo) * 512 + sx);
            a0 = __builtin_amdgcn_mfma_f32_16x16x32_bf16(af0[ks], bf, a0, 0, 0, 0);
            a1 = __builtin_amdgcn_mfma_f32_16x16x32_bf16(af1[ks], bf, a1, 0, 0, 0);
        }
        int c = p * 4 + w;
        float t0v[4], t1v[4];
        #pragma unroll
        for (int r = 0; r < 4; r++) {
            float y0 = fminf(fmaxf(a0[r], -57.f), 57.f);
            float y1 = fminf(fmaxf(a1[r], -57.f), 57.f);
            t0v[r] = 10.f - 20.f / (ex2(y0) + 1.f);
            t1v[r] = 10.f - 20.f / (ex2(y1) + 1.f);
            sum0[r] += ((mw0[r] >> c) & 1u) ? __expf(t0v[r] - 10.f) : 0.f;
            sum1[r] += ((mw1[r] >> c) & 1u) ? __expf(t1v[r] - 10.f) : 0.f;
        }
        tuA[p] = pk2t(t0v[0], t0v[1]);
        tuB[p] = pk2t(t0v[2], t0v[3]);
        tuC[p] = pk2t(t1v[0], t1v[1]);
        tuD[p] = pk2t(t1v[2], t1v[3]);
        __syncthreads();  // drains next-panel loads; buffer ready
    }

    #pragma unroll
    for (int r = 0; r < 4; r++) {
        #pragma unroll
        for (int o = 1; o < 16; o <<= 1) {
            sum0[r] += __shfl_xor(sum0[r], o);
            sum1[r] += __shfl_xor(sum1[r], o);
        }
    }
    if (lo == 0) {
        #pragma unroll
        for (int r = 0; r < 4; r++) {
            reds[w][0][4 * hi + r] = sum0[r];
            reds[w][1][4 * hi + r] = sum1[r];
        }
    }
    __syncthreads();
    float lse0[4], lse1[4];
    #pragma unroll
    for (int r = 0; r < 4; r++) {
        int row = 4 * hi + r;
        lse0[r] = 10.f + __logf(fmaxf(reds[0][0][row] + reds[1][0][row] +
                                      reds[2][0][row] + reds[3][0][row], 1e-37f));
        lse1[r] = 10.f + __logf(fmaxf(reds[0][1][row] + reds[1][1][row] +
                                      reds[2][1][row] + reds[3][1][row], 1e-37f));
    }

    #pragma unroll
    for (int p = 0; p < 8; p++) {
        int c = p * 4 + w;
        int col = p * 64 + w * 16 + lo;
        float v0[4] = {ulo(tuA[p]), uhi(tuA[p]), ulo(tuB[p]), uhi(tuB[p])};
        float v1[4] = {ulo(tuC[p]), uhi(tuC[p]), ulo(tuD[p]), uhi(tuD[p])};
        #pragma unroll
        for (int r = 0; r < 4; r++) {
            float ov0 = ((mw0[r] >> c) & 1u) ? v0[r] - lse0[r] : NEG_INF - lse0[r];
            float ov1 = ((mw1[r] >> c) & 1u) ? v1[r] - lse1[r] : NEG_INF - lse1[r];
            out[((size_t)(b * TT + row0 + 4 * hi + r)) * NN + col] = ov0;
            out[((size_t)(b * TT + row0 + 16 + 4 * hi + r)) * NN + col] = ov1;
        }
    }
}

// ---------------------------------------------------------------------------
extern "C" void kernel_launch(void* const* d_in, const int* in_sizes, int n_in,
                              void* d_out, int out_size, void* d_ws,
                              size_t ws_size, hipStream_t stream) {
    const float* emb = (const float*)d_in[0];
    const int* cur   = (const int*)d_in[1];
    const int* mask  = (const int*)d_in[2];
    const float* Wn  = (const float*)d_in[3];
    const float* Wf  = (const float*)d_in[4];
    const float* Ws  = (const float*)d_in[5];
    const float* Wo  = (const float*)d_in[6];
    float* out = (float*)d_out;

    const size_t SLABE = (size_t)BB * NN * DD;
    ushort* embB     = (ushort*)d_ws;
    ushort* gkT      = embB + SLABE;     // [bh][n][32]
    ushort* vTp      = gkT + SLABE;      // [bh][dh][n''] pre-permuted
    ushort* lkb      = vTp + SLABE;      // [b*N+n][256], pre-scaled by LSCL
    ushort* gq       = lkb + SLABE;      // [b*T+t][256], pre-scaled by QSCL
    ushort* headsB   = gq + SLABE;
    ushort* glimpseB = headsB + SLABE;
    ushort* WnT      = glimpseB + SLABE;
    ushort* WsT      = WnT + 768 * 256;
    ushort* WoT      = WsT + 256 * 256;
    uint*   mbt      = (uint*)(WoT + 256 * 256);
    float*  partial  = (float*)(mbt + (size_t)BB * TT * 16);

    prep_all_k<<<1600, 256, 0, stream>>>(emb, embB, partial, Wn, Ws, Wo,
                                         WnT, WsT, WoT, mask, mbt);
    gemm3_k<0><<<2048, 256, 0, stream>>>(embB, WnT, WsT, gkT, vTp, lkb, gq,
                                         partial, Wf, cur);
    attn12_k<<<1024, 256, 0, stream>>>(gq, gkT, vTp, mbt, headsB);
    gemm3_k<1><<<512, 256, 0, stream>>>(headsB, WoT, nullptr, glimpseB,
                                        nullptr, nullptr, nullptr, nullptr,
                                        nullptr, nullptr);
    // K5: single-pass pointer logits + log_softmax (f32 out direct)
    logits7_k<<<512, 256, 0, stream>>>(glimpseB, lkb, mbt, out);
}

// Round 20
// 94.636 us; speedup vs baseline: 1.0728x; 1.0113x over previous
//
#include <hip/hip_runtime.h>
#include <hip/hip_bf16.h>

constexpr int BB = 32;    // batch
constexpr int TT = 512;   // decode steps
constexpr int NN = 512;   // nodes
constexpr int DD = 256;   // model dim
constexpr int HH = 8;     // heads
constexpr int DH = 32;    // head dim
#define NEG_INF (-1e9f)

// scale folds (applied at producer epilogues):
#define QSCL 0.25505872f   // 1/sqrt(32) * log2(e)
#define LSCL 0.18033688f   // 0.0625 * 2 * log2(e)

typedef __attribute__((ext_vector_type(8))) short bf16x8;
typedef __attribute__((ext_vector_type(4))) float f32x4;

__device__ inline float ex2(float x) { return __builtin_amdgcn_exp2f(x); }

__device__ inline ushort f2bf(float x) {
    union { float f; unsigned u; } c; c.f = x;
    unsigned u = c.u + 0x7fffu + ((c.u >> 16) & 1u);  // RNE
    return (ushort)(u >> 16);
}
__device__ inline uint pk2t(float a, float b) {  // truncating pack
    return __builtin_amdgcn_perm(__float_as_uint(b), __float_as_uint(a),
                                 0x07060302u);
}
__device__ inline ushort tr16(float x) { return (ushort)(__float_as_uint(x) >> 16); }
__device__ inline float ulo(uint u) {
    union { uint u; float f; } c; c.u = u << 16; return c.f;
}
__device__ inline float uhi(uint u) {
    union { uint u; float f; } c; c.u = u & 0xffff0000u; return c.f;
}
// async global->LDS, 16B/lane; dest = wave-uniform base + lane*16 (m97/m173)
__device__ inline void gload_lds16(const void* g, void* l) {
    __builtin_amdgcn_global_load_lds(
        (const __attribute__((address_space(1))) unsigned int*)g,
        (__attribute__((address_space(3))) unsigned int*)l, 16, 0, 0);
}

// ---------------------------------------------------------------------------
// prep_all: [0,256) emb cvt+partials | [256,576) weight transposes.
// (mask bit-pack moved into gemm3_k<0> blocks j>=2048 for overlap.)
__global__ __launch_bounds__(256) void prep_all_k(
    const float* __restrict__ emb, ushort* __restrict__ embB,
    float* __restrict__ partial, const float* __restrict__ Wn,
    const float* __restrict__ Ws, const float* __restrict__ Wo,
    ushort* __restrict__ WnT, ushort* __restrict__ WsT,
    ushort* __restrict__ WoT) {
    int j = blockIdx.x;
    int tid = threadIdx.x;
    if (j < 256) {
        int b = j >> 3, part = j & 7, d = tid;
        const float* eb = emb + ((size_t)b * NN + part * 64) * DD + d;
        ushort* ob = embB + ((size_t)b * NN + part * 64) * DD + d;
        float s = 0.f;
        #pragma unroll 4
        for (int i = 0; i < 64; i++) {
            float v = eb[(size_t)i * DD];
            s += v;
            ob[(size_t)i * DD] = f2bf(v);
        }
        partial[((size_t)b * 8 + part) * DD + d] = s;
    } else {
        __shared__ float t[32][33];
        int g = j - 256;
        int gx = g % 40, gy = g / 40;
        const float* W;
        ushort* WT;
        int NC, xb;
        if (gx < 24)      { W = Wn; WT = WnT; NC = 768; xb = gx; }
        else if (gx < 32) { W = Ws; WT = WsT; NC = 256; xb = gx - 24; }
        else              { W = Wo; WT = WoT; NC = 256; xb = gx - 32; }
        int tx = tid & 31, ty = tid >> 5;
        int x = xb * 32 + tx;
        int y0 = gy * 32;
        #pragma unroll
        for (int i = 0; i < 4; i++)
            t[ty + i * 8][tx] = W[(size_t)(y0 + ty + i * 8) * NC + x];
        __syncthreads();
        #pragma unroll
        for (int i = 0; i < 4; i++)
            WT[(size_t)(xb * 32 + ty + i * 8) * 256 + y0 + tx] =
                f2bf(t[tx][ty + i * 8]);
    }
}

// ---------------------------------------------------------------------------
// gemm3: BM=128 x BN=64 x BK=64, async-dbuf staging (verified r15-r19).
// XCD-chunked. TASK 0: j<1536 K1 (proj; lk pre-scaled by LSCL);
//   1536<=j<2048 K2 (gq = (emb[cur]@Ws + ctx)*QSCL, in-block ctx);
//   j>=2048: mask bit-pack blocks (overlapped with GEMM; done before attn).
// TASK 1: K4 (glimpse = heads @ Wo).
template <int TASK>
__global__ __launch_bounds__(256) void gemm3_k(
    const ushort* __restrict__ A0, const ushort* __restrict__ WT0,
    const ushort* __restrict__ WT1, ushort* __restrict__ O0,
    ushort* __restrict__ O1, ushort* __restrict__ O2,
    ushort* __restrict__ O3, const float* __restrict__ partial,
    const float* __restrict__ Wf, const int* __restrict__ cur,
    const int* __restrict__ maskp, uint* __restrict__ mbtw) {
    int j = blockIdx.x;
    int tid = threadIdx.x;
    if (TASK == 0 && j >= 2048) {
        // mask -> bit-packed mbt [B*T][16]; word w bit c = mask[row][c*16+w]
        int idx = (j - 2048) * 256 + tid;
        int row = idx >> 4, ww = idx & 15;
        const int* mr = maskp + (size_t)row * NN + ww;
        uint u = 0;
        #pragma unroll
        for (int c = 0; c < 32; c++) u |= (uint)(mr[c * 16] != 0) << c;
        mbtw[idx] = u;
        return;
    }
    bool k2 = (TASK == 0) && (j >= 1536);
    int bx, by;
    if (TASK == 0 && !k2) {
        int x = j & 7, t = j >> 3;           // t in [0,192)
        bx = x * 16 + t / 12; by = t % 12;
    } else {
        int jj = k2 ? j - 1536 : j;
        int x = jj & 7, t = jj >> 3;         // t in [0,64)
        bx = x * 16 + (t >> 2); by = t & 3;
    }
    int row0 = bx * 128, col0 = by * 64;
    int w = tid >> 6, l = tid & 63;
    int lo = l & 15, hi = l >> 4;

    __shared__ ushort As[2][128 * 64];  // 2 x 16KB
    __shared__ ushort Bs[2][64 * 64];   // 2 x 8KB
    __shared__ float ctxs[64];

    const ushort* WT = k2 ? WT1 : WT0;

    auto stage = [&](int buf, int kk) {
        #pragma unroll
        for (int i = 0; i < 4; i++) {
            int u = i * 256 + tid;
            int row = u >> 3, slot = u & 7;
            int arow = row0 + row;
            const ushort* ap;
            if (k2) {
                int b = arow >> 9;
                ap = A0 + ((size_t)(b * NN + cur[arow])) * DD;
            } else {
                ap = A0 + (size_t)arow * DD;
            }
            const void* gsrc = ap + kk * 64 + ((slot ^ (row & 7)) << 3);
            void* ldst = (char*)&As[buf][0] + i * 4096 + w * 1024;
            gload_lds16(gsrc, ldst);
        }
        #pragma unroll
        for (int i = 0; i < 2; i++) {
            int u = i * 256 + tid;
            int row = u >> 3, slot = u & 7;
            const void* gsrc =
                WT + (size_t)(col0 + row) * 256 + kk * 64 + ((slot ^ (row & 7)) << 3);
            void* ldst = (char*)&Bs[buf][0] + i * 4096 + w * 1024;
            gload_lds16(gsrc, ldst);
        }
    };

    const f32x4 zero = {0.f, 0.f, 0.f, 0.f};
    f32x4 acc[2][4] = {{zero, zero, zero, zero}, {zero, zero, zero, zero}};

    stage(0, 0);
    __syncthreads();
    #pragma unroll
    for (int kk = 0; kk < 4; kk++) {
        if (kk < 3) stage((kk + 1) & 1, kk + 1);
        int cb = kk & 1;
        #pragma unroll
        for (int ks = 0; ks < 2; ks++) {
            int sx = ((ks * 4 + hi) ^ (lo & 7)) << 4;
            bf16x8 af0 = *(const bf16x8*)((char*)&As[cb][0] + (w * 32 + lo) * 128 + sx);
            bf16x8 af1 = *(const bf16x8*)((char*)&As[cb][0] + (w * 32 + 16 + lo) * 128 + sx);
            #pragma unroll
            for (int c = 0; c < 4; c++) {
                bf16x8 bf = *(const bf16x8*)((char*)&Bs[cb][0] + (c * 16 + lo) * 128 + sx);
                acc[0][c] = __builtin_amdgcn_mfma_f32_16x16x32_bf16(af0, bf, acc[0][c], 0, 0, 0);
                acc[1][c] = __builtin_amdgcn_mfma_f32_16x16x32_bf16(af1, bf, acc[1][c], 0, 0, 0);
            }
        }
        __syncthreads();
    }

    int bbq = row0 >> 9;
    if (k2) {
        // in-block ctx: ctx[col] = (sum_p partial[b][p][:]/512) @ Wf[:, col]
        float* fs = (float*)&As[0][0];
        float mk = 0.f;
        #pragma unroll
        for (int p = 0; p < 8; p++)
            mk += partial[(size_t)bbq * 2048 + p * 256 + tid];
        fs[tid] = mk * (1.0f / 512.0f);
        __syncthreads();
        int cc = tid & 63, part = tid >> 6;
        float cs = 0.f;
        #pragma unroll 16
        for (int k = part * 64; k < part * 64 + 64; k++)
            cs += fs[k] * Wf[(size_t)k * 256 + col0 + cc];
        float* fs2 = fs + 256;
        fs2[part * 64 + cc] = cs;
        __syncthreads();
        if (tid < 64)
            ctxs[tid] = fs2[tid] + fs2[64 + tid] + fs2[128 + tid] + fs2[192 + tid];
        __syncthreads();
    }

    #pragma unroll
    for (int rg = 0; rg < 2; rg++) {
        int rw0 = row0 + w * 32 + rg * 16;
        int bb = rw0 >> 9;
        #pragma unroll
        for (int c = 0; c < 4; c++) {
            int col = col0 + c * 16 + lo;
            float v[4];
            #pragma unroll
            for (int r = 0; r < 4; r++) v[r] = acc[rg][c][r];
            if constexpr (TASK == 0) {
                if (k2) {
                    float bv = ctxs[col - col0];
                    #pragma unroll
                    for (int r = 0; r < 4; r++)
                        O3[(size_t)(rw0 + 4 * hi + r) * DD + col] =
                            f2bf((v[r] + bv) * QSCL);
                } else if (col < 256) {
                    int head = col >> 5, dh = col & 31;
                    #pragma unroll
                    for (int r = 0; r < 4; r++) {
                        int n = (rw0 + 4 * hi + r) & (NN - 1);
                        O0[(((size_t)(bb * HH + head) * NN + n) << 5) + dh] = f2bf(v[r]);
                    }
                } else if (col < 512) {
                    int cc2 = col - 256;
                    int bhv = bb * HH + (cc2 >> 5);
                    int dh = cc2 & 31;
                    int n0 = (rw0 + 4 * hi) & (NN - 1);
                    int m = n0 >> 2;
                    int p_ = m >> 3, s_ = (m >> 2) & 1, g_ = m & 3;
                    int n0p = (8 * p_ + 2 * g_ + s_) << 2;
                    ushort4 uv = {f2bf(v[0]), f2bf(v[1]), f2bf(v[2]), f2bf(v[3])};
                    *(ushort4*)(O1 + ((size_t)bhv * DH + dh) * NN + n0p) = uv;
                } else {
                    #pragma unroll
                    for (int r = 0; r < 4; r++)
                        O2[(size_t)(rw0 + 4 * hi + r) * 256 + (col - 512)] =
                            f2bf(v[r] * LSCL);
                }
            } else {
                #pragma unroll
                for (int r = 0; r < 4; r++)
                    O0[(size_t)(rw0 + 4 * hi + r) * DD + col] = f2bf(v[r]);
            }
        }
    }
}

// ---------------------------------------------------------------------------
// K3: two-phase LDS-staged swapped-operand attention (verified r14-r19).
__global__ __launch_bounds__(256, 4) void attn12_k(
    const ushort* __restrict__ gq, const ushort* __restrict__ gkT,
    const ushort* __restrict__ vTp, const uint* __restrict__ mbt,
    ushort* __restrict__ headsB) {
    int j = blockIdx.x;
    int bh = j & 255, quarter = j >> 8;
    int b = bh >> 3, h = bh & 7;
    int tid = threadIdx.x;
    int w = tid >> 6, l = tid & 63;
    int lo = l & 15, hi = l >> 4;

    __shared__ ushort Ks[8192];       // 16KB: read addr = lin ^ swz pair
    __shared__ ushort Vs[8192];       // 16KB
    __shared__ ushort OT[4][16][40];  // 5KB transpose staging

    const f32x4 zero = {0.f, 0.f, 0.f, 0.f};
    const bf16x8 ones = {(short)0x3F80, (short)0x3F80, (short)0x3F80,
                         (short)0x3F80, (short)0x3F80, (short)0x3F80,
                         (short)0x3F80, (short)0x3F80};
    int q0 = quarter * 128;
    int kswz = (lo & 7) << 4;

    bf16x8 qf0 = *(const bf16x8*)(gq + ((size_t)(b * TT + q0 + w * 16 + lo)) * DD + h * DH + hi * 8);
    bf16x8 qf1 = *(const bf16x8*)(gq + ((size_t)(b * TT + q0 + 64 + w * 16 + lo)) * DD + h * DH + hi * 8);
    uint4 mq0 = *(const uint4*)(mbt + ((size_t)(b * TT + q0 + w * 16 + lo)) * 16 + 4 * hi);
    uint4 mq1 = *(const uint4*)(mbt + ((size_t)(b * TT + q0 + 64 + w * 16 + lo)) * 16 + 4 * hi);

    f32x4 o0[2] = {zero, zero};
    f32x4 o1[2] = {zero, zero};
    f32x4 osum[2] = {zero, zero};

    const char* kbase = (const char*)(gkT + (size_t)bh * (NN * DH));
    const char* vbase = (const char*)(vTp + (size_t)bh * (DH * NN));

    for (int ph = 0; ph < 2; ph++) {
        if (ph) __syncthreads();
        {
            const char* ksrc = kbase + ph * 16384;
            #pragma unroll
            for (int i = 0; i < 4; i++) {
                int x = (i * 256 + tid) * 16;
                int g = x ^ (((x >> 2) & 0x70) ^ ((x >> 4) & 0x10));
                gload_lds16(ksrc + g, (char*)Ks + i * 4096 + w * 1024);
            }
        }
        {
            const char* vsrc = vbase + ph * 512;
            #pragma unroll
            for (int i = 0; i < 4; i++) {
                int x = (i * 256 + tid) * 16;
                int g = ((x >> 9) << 10) + ((x & 511) ^ ((x >> 5) & 0x70));
                gload_lds16(vsrc + g, (char*)Vs + i * 4096 + w * 1024);
            }
        }
        __syncthreads();

        #pragma unroll
        for (int qc2 = 0; qc2 < 2; qc2++) {
            bf16x8 qf = qc2 ? qf1 : qf0;
            uint4 mq = qc2 ? mq1 : mq0;

            #pragma unroll 4
            for (int p = 0; p < 8; p++) {
                int nn = 32 * p + lo;
                bf16x8 kf0 = *(const bf16x8*)((char*)Ks + ((nn * 64 + hi * 16) ^ kswz));
                bf16x8 kf1 = *(const bf16x8*)((char*)Ks + (((nn + 16) * 64 + hi * 16) ^ kswz));
                __builtin_amdgcn_s_setprio(1);
                f32x4 s0 = __builtin_amdgcn_mfma_f32_16x16x32_bf16(kf0, qf, zero, 0, 0, 0);
                f32x4 s1 = __builtin_amdgcn_mfma_f32_16x16x32_bf16(kf1, qf, zero, 0, 0, 0);
                __builtin_amdgcn_s_setprio(0);
                union { bf16x8 v; uint u[4]; } pf;
                {
                    int c = ph * 16 + 2 * p;
                    float e0 = ((mq.x >> c) & 1u) ? ex2(s0[0]) : 0.f;
                    float e1 = ((mq.y >> c) & 1u) ? ex2(s0[1]) : 0.f;
                    float e2 = ((mq.z >> c) & 1u) ? ex2(s0[2]) : 0.f;
                    float e3 = ((mq.w >> c) & 1u) ? ex2(s0[3]) : 0.f;
                    pf.u[0] = pk2t(e0, e1);
                    pf.u[1] = pk2t(e2, e3);
                }
                {
                    int c = ph * 16 + 2 * p + 1;
                    float e0 = ((mq.x >> c) & 1u) ? ex2(s1[0]) : 0.f;
                    float e1 = ((mq.y >> c) & 1u) ? ex2(s1[1]) : 0.f;
                    float e2 = ((mq.z >> c) & 1u) ? ex2(s1[2]) : 0.f;
                    float e3 = ((mq.w >> c) & 1u) ? ex2(s1[3]) : 0.f;
                    pf.u[2] = pk2t(e0, e1);
                    pf.u[3] = pk2t(e2, e3);
                }
                int vo = (32 * p + 8 * hi) * 2;
                bf16x8 va0 = *(const bf16x8*)((char*)Vs + ((lo * 512 + vo) ^ kswz));
                bf16x8 va1 = *(const bf16x8*)((char*)Vs + (((lo + 16) * 512 + vo) ^ kswz));
                __builtin_amdgcn_s_setprio(1);
                o0[qc2] = __builtin_amdgcn_mfma_f32_16x16x32_bf16(va0, pf.v, o0[qc2], 0, 0, 0);
                o1[qc2] = __builtin_amdgcn_mfma_f32_16x16x32_bf16(va1, pf.v, o1[qc2], 0, 0, 0);
                osum[qc2] = __builtin_amdgcn_mfma_f32_16x16x32_bf16(ones, pf.v, osum[qc2], 0, 0, 0);
                __builtin_amdgcn_s_setprio(0);
            }
        }
    }

    #pragma unroll
    for (int qc2 = 0; qc2 < 2; qc2++) {
        int t0 = q0 + qc2 * 64 + w * 16;
        float inv = 1.0f / fmaxf(osum[qc2][0], 1e-30f);
        #pragma unroll
        for (int r = 0; r < 4; r++) {
            OT[w][lo][4 * hi + r] = tr16(o0[qc2][r] * inv);
            OT[w][lo][16 + 4 * hi + r] = tr16(o1[qc2][r] * inv);
        }
        bf16x8 ov = *(const bf16x8*)(&OT[w][lo][hi * 8]);
        *(bf16x8*)(headsB + ((size_t)(b * TT + t0 + lo)) * DD + h * DH + hi * 8) = ov;
    }
}

// ---------------------------------------------------------------------------
// K5 (single pass): full-row pointer logits + log_softmax, f32 out direct
// (verified r19). Block = 32 rows x 512 cols; lk panels through 2x32KB
// async double buffer. XCD-chunked.
__global__ __launch_bounds__(256) void logits7_k(
    const ushort* __restrict__ glimpse, const ushort* __restrict__ lkb,
    const uint* __restrict__ mbt, float* __restrict__ out) {
    int j = blockIdx.x;  // 512
    int x = j & 7, t = j >> 3;       // t in [0,64)
    int b = x * 4 + (t >> 4);
    int row0 = (t & 15) * 32;
    int tid = threadIdx.x;
    int w = tid >> 6, l = tid & 63;
    int lo = l & 15, hi = l >> 4;

    __shared__ ushort As[32 * 256];     // 16KB
    __shared__ ushort Bs[2][64 * 256];  // 64KB
    __shared__ float reds[4][2][16];

    const ushort* Abase = glimpse + ((size_t)b * TT + row0) * DD;
    const ushort* Bbase = lkb + (size_t)b * NN * DD;
    int kswz = (lo & 7) << 4;

    #pragma unroll
    for (int i = 0; i < 4; i++) {
        int xx = (i * 256 + tid) * 16;
        int g = xx ^ ((xx >> 5) & 0x70);
        gload_lds16((const char*)Abase + g, (char*)As + i * 4096 + w * 1024);
    }
    auto stageB = [&](int buf, int p) {
        const char* src = (const char*)(Bbase + (size_t)p * 64 * DD);
        #pragma unroll
        for (int i = 0; i < 8; i++) {
            int xx = (i * 256 + tid) * 16;
            int g = xx ^ ((xx >> 5) & 0x70);
            gload_lds16(src + g, (char*)&Bs[buf][0] + i * 4096 + w * 1024);
        }
    };
    stageB(0, 0);
    __syncthreads();

    bf16x8 af0[8], af1[8];
    #pragma unroll
    for (int ks = 0; ks < 8; ks++) {
        int sx = ((ks * 4 + hi) << 4) ^ kswz;
        af0[ks] = *(const bf16x8*)((char*)As + lo * 512 + sx);
        af1[ks] = *(const bf16x8*)((char*)As + (16 + lo) * 512 + sx);
    }
    uint mw0[4], mw1[4];
    #pragma unroll
    for (int r = 0; r < 4; r++) {
        mw0[r] = mbt[((size_t)(b * TT + row0 + 4 * hi + r)) * 16 + lo];
        mw1[r] = mbt[((size_t)(b * TT + row0 + 16 + 4 * hi + r)) * 16 + lo];
    }

    const f32x4 zero = {0.f, 0.f, 0.f, 0.f};
    float sum0[4] = {0.f, 0.f, 0.f, 0.f}, sum1[4] = {0.f, 0.f, 0.f, 0.f};
    uint tuA[8], tuB[8], tuC[8], tuD[8];

    #pragma unroll
    for (int p = 0; p < 8; p++) {
        if (p < 7) stageB((p + 1) & 1, p + 1);
        int cb = p & 1;
        f32x4 a0 = zero, a1 = zero;
        #pragma unroll
        for (int ks = 0; ks < 8; ks++) {
            int sx = ((ks * 4 + hi) << 4) ^ kswz;
            bf16x8 bf = *(const bf16x8*)((char*)&Bs[cb][0] + (w * 16 + lo) * 512 + sx);
            a0 = __builtin_amdgcn_mfma_f32_16x16x32_bf16(af0[ks], bf, a0, 0, 0, 0);
            a1 = __builtin_amdgcn_mfma_f32_16x16x32_bf16(af1[ks], bf, a1, 0, 0, 0);
        }
        int c = p * 4 + w;
        float t0v[4], t1v[4];
        #pragma unroll
        for (int r = 0; r < 4; r++) {
            float y0 = fminf(fmaxf(a0[r], -57.f), 57.f);
            float y1 = fminf(fmaxf(a1[r], -57.f), 57.f);
            t0v[r] = 10.f - 20.f / (ex2(y0) + 1.f);
            t1v[r] = 10.f - 20.f / (ex2(y1) + 1.f);
            sum0[r] += ((mw0[r] >> c) & 1u) ? __expf(t0v[r] - 10.f) : 0.f;
            sum1[r] += ((mw1[r] >> c) & 1u) ? __expf(t1v[r] - 10.f) : 0.f;
        }
        tuA[p] = pk2t(t0v[0], t0v[1]);
        tuB[p] = pk2t(t0v[2], t0v[3]);
        tuC[p] = pk2t(t1v[0], t1v[1]);
        tuD[p] = pk2t(t1v[2], t1v[3]);
        __syncthreads();
    }

    #pragma unroll
    for (int r = 0; r < 4; r++) {
        #pragma unroll
        for (int o = 1; o < 16; o <<= 1) {
            sum0[r] += __shfl_xor(sum0[r], o);
            sum1[r] += __shfl_xor(sum1[r], o);
        }
    }
    if (lo == 0) {
        #pragma unroll
        for (int r = 0; r < 4; r++) {
            reds[w][0][4 * hi + r] = sum0[r];
            reds[w][1][4 * hi + r] = sum1[r];
        }
    }
    __syncthreads();
    float lse0[4], lse1[4];
    #pragma unroll
    for (int r = 0; r < 4; r++) {
        int row = 4 * hi + r;
        lse0[r] = 10.f + __logf(fmaxf(reds[0][0][row] + reds[1][0][row] +
                                      reds[2][0][row] + reds[3][0][row], 1e-37f));
        lse1[r] = 10.f + __logf(fmaxf(reds[0][1][row] + reds[1][1][row] +
                                      reds[2][1][row] + reds[3][1][row], 1e-37f));
    }

    #pragma unroll
    for (int p = 0; p < 8; p++) {
        int c = p * 4 + w;
        int col = p * 64 + w * 16 + lo;
        float v0[4] = {ulo(tuA[p]), uhi(tuA[p]), ulo(tuB[p]), uhi(tuB[p])};
        float v1[4] = {ulo(tuC[p]), uhi(tuC[p]), ulo(tuD[p]), uhi(tuD[p])};
        #pragma unroll
        for (int r = 0; r < 4; r++) {
            float ov0 = ((mw0[r] >> c) & 1u) ? v0[r] - lse0[r] : NEG_INF - lse0[r];
            float ov1 = ((mw1[r] >> c) & 1u) ? v1[r] - lse1[r] : NEG_INF - lse1[r];
            out[((size_t)(b * TT + row0 + 4 * hi + r)) * NN + col] = ov0;
            out[((size_t)(b * TT + row0 + 16 + 4 * hi + r)) * NN + col] = ov1;
        }
    }
}

// ---------------------------------------------------------------------------
extern "C" void kernel_launch(void* const* d_in, const int* in_sizes, int n_in,
                              void* d_out, int out_size, void* d_ws,
                              size_t ws_size, hipStream_t stream) {
    const float* emb = (const float*)d_in[0];
    const int* cur   = (const int*)d_in[1];
    const int* mask  = (const int*)d_in[2];
    const float* Wn  = (const float*)d_in[3];
    const float* Wf  = (const float*)d_in[4];
    const float* Ws  = (const float*)d_in[5];
    const float* Wo  = (const float*)d_in[6];
    float* out = (float*)d_out;

    const size_t SLABE = (size_t)BB * NN * DD;
    ushort* embB     = (ushort*)d_ws;
    ushort* gkT      = embB + SLABE;     // [bh][n][32]
    ushort* vTp      = gkT + SLABE;      // [bh][dh][n''] pre-permuted
    ushort* lkb      = vTp + SLABE;      // [b*N+n][256], pre-scaled by LSCL
    ushort* gq       = lkb + SLABE;      // [b*T+t][256], pre-scaled by QSCL
    ushort* headsB   = gq + SLABE;
    ushort* glimpseB = headsB + SLABE;
    ushort* WnT      = glimpseB + SLABE;
    ushort* WsT      = WnT + 768 * 256;
    ushort* WoT      = WsT + 256 * 256;
    uint*   mbt      = (uint*)(WoT + 256 * 256);
    float*  partial  = (float*)(mbt + (size_t)BB * TT * 16);

    prep_all_k<<<576, 256, 0, stream>>>(emb, embB, partial, Wn, Ws, Wo,
                                        WnT, WsT, WoT);
    // K1 (1536) + K2 (512) + mask bit-pack (1024, overlapped)
    gemm3_k<0><<<3072, 256, 0, stream>>>(embB, WnT, WsT, gkT, vTp, lkb, gq,
                                         partial, Wf, cur, mask, mbt);
    attn12_k<<<1024, 256, 0, stream>>>(gq, gkT, vTp, mbt, headsB);
    gemm3_k<1><<<512, 256, 0, stream>>>(headsB, WoT, nullptr, glimpseB,
                                        nullptr, nullptr, nullptr, nullptr,
                                        nullptr, nullptr, nullptr, nullptr);
    logits7_k<<<512, 256, 0, stream>>>(glimpseB, lkb, mbt, out);
}